// Round 21
// baseline (110.126 us; speedup 1.0000x reference)
//
#include <hip/hip_runtime.h>

// ---------------------------------------------------------------------------
// LinearDepthWiseAttention, round 21: r20 base + HEAD-PAIRED fused kernel.
//   Each fused block now serves 2 heads from every staged netT chunk
//   (same stage/barrier schedule; 2x MFMA per chunk; 16 chunks of a 512-n
//   slice). Per-CU LDS/MFMA totals unchanged; stall windows halve (64->32).
//   kv   = w_qkv[512:1536] @ net ; ek = exp(k)      (never hits HBM)
//   ctx[b,h] += ek_h @ v_h^T ; rowsums via all-ones B-frag MFMA
//   W2 = fold(w_out, ctx/sum) ; W3[b] = W2[b] @ w_q^T ; out = W3 @ net + b_out
// Workspace:
//   netT  [16][4096][256] bf16 @ 0          (33554432)
//   ctxp  [128][8][64][64] f32 @ 33554432   (16777216)
//   sump  [128][8][64]     f32 @ 50331648   (262144)
//   W2    [16][256][512]  bf16 @ 50593792   (4194304)
//   W3    [16][256][256]  bf16 @ 54788096   (2097152)
//   wkv   [1024][256]     bf16 @ 56885248   (524288)
//   wqTb  [256][512]      bf16 @ 57409536   (262144)
// ---------------------------------------------------------------------------

typedef unsigned short u16;
typedef unsigned int u32;
typedef __attribute__((ext_vector_type(4))) u16 u16x4;
typedef __attribute__((ext_vector_type(4))) u32 u32x4;
typedef __attribute__((ext_vector_type(4))) float f32x4;
typedef __attribute__((ext_vector_type(8))) short bf16x8;

__device__ __forceinline__ u16 f2bf(float f) {
  union { float f; u32 u; } x; x.f = f;
  u32 r = x.u + 0x7fffu + ((x.u >> 16) & 1u);   // round-to-nearest-even
  return (u16)(r >> 16);
}

// async global->LDS, 16B per lane; LDS dest must be wave-uniform base + lane*16.
__device__ __forceinline__ void async16(const u16* g, u16* l) {
  __builtin_amdgcn_global_load_lds(
      (const __attribute__((address_space(1))) void*)g,
      (__attribute__((address_space(3))) void*)l, 16, 0, 0);
}

// ---------------- prep_all: net transpose + weight prep, ONE launch ---------
__global__ __launch_bounds__(256) void prep_all(const float* __restrict__ net,
                                                u16* __restrict__ netT,
                                                const float* __restrict__ wqkv,
                                                u16* __restrict__ wkv,
                                                u16* __restrict__ wqTb) {
  __shared__ float t[64][65];
  const int blk = blockIdx.x;
  const int tid = threadIdx.x;
  if (blk < 4096) {                      // ---- net transpose (R=256,C=4096) ----
    const int b = blk >> 8, c0 = ((blk >> 6) & 3) * 64, n0 = (blk & 63) * 64;
    const float* ip = net + (size_t)b * 256 * 4096;
    u16* op = netT + (size_t)b * 256 * 4096;
    const int col4 = (tid & 15) * 4, rr0 = tid >> 4;
#pragma unroll
    for (int i = 0; i < 4; ++i) {
      int r = rr0 + i * 16;
      f32x4 v = *(const f32x4*)(ip + (size_t)(c0 + r) * 4096 + n0 + col4);
      t[r][col4 + 0] = v[0]; t[r][col4 + 1] = v[1];
      t[r][col4 + 2] = v[2]; t[r][col4 + 3] = v[3];
    }
    __syncthreads();
    const int c8 = (tid & 7) * 8, nr0 = tid >> 3;   // nr0 0..31
#pragma unroll
    for (int i = 0; i < 2; ++i) {
      int nr = nr0 + i * 32;
      u16 tmp[8];
#pragma unroll
      for (int k = 0; k < 8; ++k) tmp[k] = f2bf(t[c8 + k][nr]);
      *(u32x4*)(op + (size_t)(n0 + nr) * 256 + c0 + c8) = *(const u32x4*)tmp;
    }
  } else if (blk < 4352) {               // ---- w_kv cast ----
    const float* w = wqkv + 512 * 256;
    int i = ((blk - 4096) * 256 + tid) * 4;
    f32x4 v = *(const f32x4*)(w + i);
    u16x4 u;
    u[0] = f2bf(v[0]); u[1] = f2bf(v[1]); u[2] = f2bf(v[2]); u[3] = f2bf(v[3]);
    *(u16x4*)(wkv + i) = u;
  } else {                               // ---- w_q transpose (R=512,C=256) ----
    const int idx = blk - 4352;          // 0..31
    const int c0 = (idx & 3) * 64, r0 = (idx >> 2) * 64;
    const int col4 = (tid & 15) * 4, rr0 = tid >> 4;
#pragma unroll
    for (int i = 0; i < 4; ++i) {
      int r = rr0 + i * 16;
      f32x4 v = *(const f32x4*)(wqkv + (size_t)(r0 + r) * 256 + c0 + col4);
      t[r][col4 + 0] = v[0]; t[r][col4 + 1] = v[1];
      t[r][col4 + 2] = v[2]; t[r][col4 + 3] = v[3];
    }
    __syncthreads();
    const int cc4 = (tid & 15) * 4, nr0 = tid >> 4;
#pragma unroll
    for (int i = 0; i < 4; ++i) {
      int nr = nr0 + i * 16;
      u16x4 u;
      u[0] = f2bf(t[cc4 + 0][nr]); u[1] = f2bf(t[cc4 + 1][nr]);
      u[2] = f2bf(t[cc4 + 2][nr]); u[3] = f2bf(t[cc4 + 3][nr]);
      *(u16x4*)(wqTb + (size_t)(c0 + nr) * 512 + r0 + cc4) = u;
    }
  }
}

// ---------------- fused kv + ctx, HEAD-PAIRED ----------------
// Grid 512 = (16 b) x (4 head-pairs) x (8 n-slices of 512); 512 thr = 8 waves.
// Wave roles (rows 0..255 = h0-k, h0-v, h1-k, h1-v, 64 each):
//   head_loc = wid>>2; isK = !((wid>>1)&1); rbase = (wid&1)*32.
// Per chunk c (16 chunks of 32 n):
//   [__syncthreads] [stage(c+1) -> Bs[p^1]]
//   [setprio; ctx(c-1) both heads; kv(c): 32 MFMA/wave] [exp+write ekv[head][p]]
// ctx: waves 0-3 own h0 (d-group wid&3), waves 4-7 own h1; each wave covers
// all 64 e (cacc[4]) + its own rowsum MFMA.
__global__ __launch_bounds__(512, 4) void kv_ctx_fused(
    const u16* __restrict__ wkv,   // [1024][256] bf16 (k rows 0..511, v 512..1023)
    const u16* __restrict__ netT,  // [16][4096][256] bf16
    float* __restrict__ ctxp,      // [128][8][64][64]
    float* __restrict__ sump) {    // [128][8][64]
  __shared__ __align__(16) u16 Bs[2][8192];       // 32KB [buf][32 n][256 c] swz
  __shared__ __align__(16) u16 ekL[2][2][2048];   // 16KB [head][buf][64 d][32 n]
  __shared__ __align__(16) u16 vL[2][2][2048];    // 16KB [head][buf][64 e][32 n]

  // XCD-aware decode: xcd = flat&7 hosts batches {2*xcd, 2*xcd+1} only.
  const int flat = blockIdx.x;
  const int xcd = flat & 7, inner = flat >> 3;     // inner 0..63
  const int b = 2 * xcd + (inner >> 5);
  const int hp = (inner >> 3) & 3;                 // head pair 0..3
  const int s = inner & 7;                         // n-slice 0..7 (512 n)

  const int tid = threadIdx.x, lane = tid & 63, wid = tid >> 6;
  const int lr = lane & 15, lg = lane >> 4;
  const int head_loc = wid >> 2;                   // 0..1
  const int h = hp * 2 + head_loc;                 // global head
  const bool isK = ((wid >> 1) & 1) == 0;
  const int rbase = (wid & 1) * 32;                // within 64-row k/v category
  const int w4 = wid & 3;                          // ctx d-group within head

  // ---- A-frags: 32 rows x 256 K per wave (64 VGPR) ----
  bf16x8 af[2][8];
#pragma unroll
  for (int mi = 0; mi < 2; ++mi) {
    const int rl = rbase + mi * 16 + lr;           // 0..63 within category
    const int grow = isK ? (h * 64 + rl) : (512 + h * 64 + rl);
#pragma unroll
    for (int kk = 0; kk < 8; ++kk)
      af[mi][kk] = *(const bf16x8*)(wkv + (size_t)grow * 256 + kk * 32 + lg * 8);
  }

  const u16* Bsrc = netT + ((size_t)b * 4096 + s * 512) * 256;
  const int srow = tid >> 5;       // 0..15 (+ i*16)
  const int sslot = tid & 31;      // 16B slot within row
  auto stage = [&](int c, int buf) {
    const u16* src = Bsrc + (size_t)c * 32 * 256;
#pragma unroll
    for (int i = 0; i < 2; ++i) {
      const int row = i * 16 + srow;
      const int scol = ((sslot ^ (row & 7)) * 8);
      async16(src + row * 256 + scol, &Bs[buf][i * 4096 + tid * 8]);
    }
  };

  f32x4 cacc[4] = {};          // ctx: d-group w4 x 64 e (4 x 16)
  f32x4 sacc = {};             // rowsums for d-group w4
  bf16x8 ones8;
#pragma unroll
  for (int j = 0; j < 8; ++j) ((u16*)&ones8)[j] = 0x3F80;  // bf16 1.0

  // ctx accumulate from this wave's head buffers, chunk-buffer q (K = 32 n)
  auto ctx_acc = [&](int q) {
    const int d = w4 * 16 + lr;
    bf16x8 ekf = *(const bf16x8*)&ekL[head_loc][q][d * 32 + ((lg ^ (d & 3)) * 8)];
#pragma unroll
    for (int ei = 0; ei < 4; ++ei) {
      const int e = ei * 16 + lr;
      bf16x8 vf = *(const bf16x8*)&vL[head_loc][q][e * 32 + ((lg ^ (e & 3)) * 8)];
      cacc[ei] = __builtin_amdgcn_mfma_f32_16x16x32_bf16(ekf, vf, cacc[ei], 0, 0, 0);
    }
    sacc = __builtin_amdgcn_mfma_f32_16x16x32_bf16(ekf, ones8, sacc, 0, 0, 0);
  };

  stage(0, 0);

  for (int c = 0; c < 16; ++c) {
    const int p = c & 1;
    // single barrier: drains my stage(c) vmem + all ds ops -> Bs[p] resident;
    // ekv(c-1) visible; Bs[p^1]/ekv[p] readers all completed block-wide.
    __syncthreads();
    if (c + 1 < 16) stage(c + 1, p ^ 1);   // safe: issued after the barrier

    // ---- merged MFMA region: ctx(c-1) + kv(c) (both n-halves) ----
    f32x4 kvacc[2][2] = {};
    __builtin_amdgcn_s_setprio(1);
    if (c > 0) ctx_acc(p ^ 1);             // ekv written in iter c-1
#pragma unroll
    for (int kk = 0; kk < 8; ++kk) {
      // (16+lr)&7 == lr&7 -> same swizzle term for both n-halves
      bf16x8 bf0 = *(const bf16x8*)&Bs[p][lr * 256 + (((kk * 4 + lg) ^ (lr & 7)) * 8)];
      bf16x8 bf1 = *(const bf16x8*)&Bs[p][(16 + lr) * 256 + (((kk * 4 + lg) ^ (lr & 7)) * 8)];
#pragma unroll
      for (int mi = 0; mi < 2; ++mi) {
        kvacc[mi][0] = __builtin_amdgcn_mfma_f32_16x16x32_bf16(af[mi][kk], bf0, kvacc[mi][0], 0, 0, 0);
        kvacc[mi][1] = __builtin_amdgcn_mfma_f32_16x16x32_bf16(af[mi][kk], bf1, kvacc[mi][1], 0, 0, 0);
      }
    }
    __builtin_amdgcn_s_setprio(0);

    // ---- exp (k-half) + cheap-RNE bf16 + write to ekv[head][p] ----
    u16* dstL = isK ? ekL[head_loc][p] : vL[head_loc][p];
#pragma unroll
    for (int mi = 0; mi < 2; ++mi)
#pragma unroll
      for (int nj = 0; nj < 2; ++nj)
#pragma unroll
        for (int j = 0; j < 4; ++j) {
          float v = kvacc[mi][nj][j];
          if (isK) v = __expf(v);
          const u32 u = __float_as_uint(v);
          const u16 bv = (u16)((u + 0x8000u) >> 16);     // cheap RNE
          const int dd = rbase + mi * 16 + lg * 4 + j;   // 0..63
          const int n = nj * 16 + lr;                    // 0..31
          dstL[dd * 32 + (((n >> 3) ^ (dd & 3)) * 8) + (n & 7)] = bv;
        }
  }
  __syncthreads();                 // ekv(15) visible
  ctx_acc(1);                      // ctx(15): buf 15&1 = 1

  // ---- store partials (each wave: its head, d-group w4, all 64 e) ----
  const int bh = b * 8 + h;
  float* cp = ctxp + (((size_t)bh * 8 + s) * 4096);
#pragma unroll
  for (int ei = 0; ei < 4; ++ei)
#pragma unroll
    for (int j = 0; j < 4; ++j) {
      const int d = w4 * 16 + lg * 4 + j;
      const int e = ei * 16 + lr;
      cp[d * 64 + e] = cacc[ei][j];
    }
  if (lr == 0) {
#pragma unroll
    for (int j = 0; j < 4; ++j)
      sump[((size_t)bh * 8 + s) * 64 + w4 * 16 + lg * 4 + j] = sacc[j];
  }
}

// ---------------- fold_w2: reduce 8 partials, normalize, fold w_out ----------
__global__ __launch_bounds__(256) void fold_w2(const float* __restrict__ ctxp,
                                               const float* __restrict__ sump,
                                               const float* __restrict__ wout,
                                               u16* __restrict__ W2) {
  __shared__ float cl[16 * 64];
  __shared__ float sl[16];
  const int bh = blockIdx.x, dq = blockIdx.y;
  const int b = bh >> 3, h = bh & 7;
  const int tid = threadIdx.x;
  f32x4 v4 = {0.f, 0.f, 0.f, 0.f};
#pragma unroll
  for (int ch = 0; ch < 8; ++ch)
    v4 += *(const f32x4*)(ctxp + ((size_t)bh * 8 + ch) * 4096 + dq * 1024 + tid * 4);
  *(f32x4*)&cl[tid * 4] = v4;
  if (tid < 16) {
    float ss = 0.f;
#pragma unroll
    for (int ch = 0; ch < 8; ++ch)
      ss += sump[((size_t)bh * 8 + ch) * 64 + dq * 16 + tid];
    sl[tid] = ss;
  }
  __syncthreads();
  const int c = tid;
  f32x4 wv[16];
  const float* wrow = wout + (size_t)c * 512 + h * 64;
#pragma unroll
  for (int i = 0; i < 16; ++i) wv[i] = *(const f32x4*)(wrow + i * 4);
#pragma unroll
  for (int d = 0; d < 16; ++d) {
    f32x4 s4 = {0.f, 0.f, 0.f, 0.f};
#pragma unroll
    for (int e4 = 0; e4 < 16; ++e4) {
      f32x4 cv = *(const f32x4*)&cl[d * 64 + e4 * 4];
      s4 += wv[e4] * cv;
    }
    const float s = (s4[0] + s4[1] + s4[2] + s4[3]) / sl[d];
    W2[((size_t)b * 256 + c) * 512 + h * 64 + dq * 16 + d] = f2bf(s);
  }
}

// ---------------- gemm128: C[128x128] = A[128xK] * B[128xK]^T ----------------
// MODE 1: f32 out + bias; flat 1D grid with XCD-aware decode.
// MODE 2: bf16 plain (W3), standard 3D grid.
template <int LD, int NK, int MODE>
__global__ __launch_bounds__(256) void gemm128(const u16* __restrict__ A,
                                               const u16* __restrict__ B,
                                               size_t aStride, size_t bStride,
                                               void* __restrict__ O0,
                                               const float* __restrict__ bias) {
  __shared__ __align__(16) u16 SM[32768];
  int b, mt, nt;
  if constexpr (MODE == 1) {
    const int flat = blockIdx.x;
    const int xcd = flat & 7, r = flat >> 3;   // r 0..127
    b = 2 * xcd + (r >> 6);
    nt = (r & 63) >> 1;
    mt = r & 1;
  } else {
    b = blockIdx.z; mt = blockIdx.y; nt = blockIdx.x;
  }
  const int tid = threadIdx.x, lane = tid & 63, wid = tid >> 6;
  const int wr = wid >> 1, wc = wid & 1, lr = lane & 15, lg = lane >> 4;
  const u16* Ap = A + (size_t)b * aStride + (size_t)mt * 128 * LD;
  const u16* Bp = B + (size_t)b * bStride + (size_t)nt * 128 * LD;

  auto stage = [&](int buf, int ks) {
    const int k0 = ks * 64;
#pragma unroll
    for (int i = 0; i < 4; ++i) {
      const int idx = i * 2048 + tid * 8;
      const int r2 = idx >> 6, c2 = idx & 63;
      async16(Ap + (size_t)r2 * LD + k0 + c2, SM + buf * 8192 + i * 2048 + wid * 512);
      async16(Bp + (size_t)r2 * LD + k0 + c2, SM + 16384 + buf * 8192 + i * 2048 + wid * 512);
    }
  };

  f32x4 acc[4][4] = {};
  stage(0, 0);
  asm volatile("s_waitcnt vmcnt(0)" ::: "memory");
  __syncthreads();
  for (int ks = 0; ks < NK; ++ks) {
    const int buf = ks & 1;
    if (ks + 1 < NK) stage(buf ^ 1, ks + 1);
    const u16* Ab = SM + buf * 8192;
    const u16* Bb = SM + 16384 + buf * 8192;
#pragma unroll
    for (int kk = 0; kk < 2; ++kk) {
      bf16x8 afm[4], bfr[4];
#pragma unroll
      for (int mi = 0; mi < 4; ++mi)
        afm[mi] = *(const bf16x8*)(Ab + (wr * 64 + mi * 16 + lr) * 64 + kk * 32 + lg * 8);
#pragma unroll
      for (int ni = 0; ni < 4; ++ni)
        bfr[ni] = *(const bf16x8*)(Bb + (wc * 64 + ni * 16 + lr) * 64 + kk * 32 + lg * 8);
#pragma unroll
      for (int mi = 0; mi < 4; ++mi)
#pragma unroll
        for (int ni = 0; ni < 4; ++ni)
          acc[mi][ni] = __builtin_amdgcn_mfma_f32_16x16x32_bf16(afm[mi], bfr[ni], acc[mi][ni], 0, 0, 0);
    }
    asm volatile("s_waitcnt vmcnt(0)" ::: "memory");
    __syncthreads();
  }

  if constexpr (MODE == 2) {               // bf16 store (W3)
    u16* Cs = SM;
#pragma unroll
    for (int mi = 0; mi < 4; ++mi)
#pragma unroll
      for (int ni = 0; ni < 4; ++ni)
#pragma unroll
        for (int j = 0; j < 4; ++j)
          Cs[(wr * 64 + mi * 16 + lg * 4 + j) * 128 + wc * 64 + ni * 16 + lr] =
              f2bf(acc[mi][ni][j]);
    __syncthreads();
    u16* dst = (u16*)O0;
#pragma unroll
    for (int p = 0; p < 8; ++p) {
      const int idx = p * 2048 + tid * 8;
      const int r2 = idx >> 7, cc = idx & 127;
      *(u32x4*)(dst + ((size_t)b * 256 + mt * 128 + r2) * 256 + nt * 128 + cc) =
          *(const u32x4*)(Cs + idx);
    }
  } else {                                  // MODE 1: f32 + bias
    float* Cf = (float*)SM;                 // 64KB: 128x128 f32
#pragma unroll
    for (int mi = 0; mi < 4; ++mi)
#pragma unroll
      for (int ni = 0; ni < 4; ++ni)
#pragma unroll
        for (int j = 0; j < 4; ++j) {
          const int row = wr * 64 + mi * 16 + lg * 4 + j;
          Cf[row * 128 + wc * 64 + ni * 16 + lr] = acc[mi][ni][j] + bias[mt * 128 + row];
        }
    __syncthreads();
    float* op = (float*)O0;
#pragma unroll
    for (int p = 0; p < 16; ++p) {
      const int idx = p * 1024 + tid * 4;
      const int r2 = idx >> 7, cc = idx & 127;
      *(f32x4*)(op + ((size_t)b * 256 + mt * 128 + r2) * 4096 + nt * 128 + cc) =
          *(const f32x4*)(Cf + idx);
    }
  }
}

// ---------------------------------------------------------------------------
extern "C" void kernel_launch(void* const* d_in, const int* in_sizes, int n_in,
                              void* d_out, int out_size, void* d_ws, size_t ws_size,
                              hipStream_t stream) {
  const float* net  = (const float*)d_in[0];   // [16][256][4096]
  const float* wqkv = (const float*)d_in[1];   // [1536][256]
  const float* wout = (const float*)d_in[2];   // [256][512]
  const float* bout = (const float*)d_in[3];   // [256]
  float* out = (float*)d_out;

  char* ws = (char*)d_ws;
  u16*   netT = (u16*)(ws + 0);
  float* ctxp = (float*)(ws + 33554432);
  float* sump = (float*)(ws + 50331648);
  u16*   W2   = (u16*)(ws + 50593792);
  u16*   W3   = (u16*)(ws + 54788096);
  u16*   wkv  = (u16*)(ws + 56885248);
  u16*   wqTb = (u16*)(ws + 57409536);

  // net transpose + w_kv cast + w_q transpose in ONE launch
  prep_all<<<4384, 256, 0, stream>>>(net, netT, wqkv, wkv, wqTb);
  // fused kv + ctx, head-paired (ek/vv never hit HBM); 512 blocks, 16 chunks
  kv_ctx_fused<<<512, 512, 0, stream>>>(wkv, netT, ctxp, sump);
  // reduce 8 partials + normalize + fold with w_out
  fold_w2<<<dim3(128, 4), 256, 0, stream>>>(ctxp, sump, wout, W2);
  // W3[b] = W2[b] @ wqT : M=256 K=512 N=256
  gemm128<512, 8, 2><<<dim3(2, 2, 16), 256, 0, stream>>>(
      W2, wqTb, (size_t)256 * 512, 0, W3, nullptr);
  // out = W3 @ netT^T + b_out : M=256 K=256 N=4096 (flat XCD-aware grid)
  gemm128<256, 4, 1><<<dim3(1024, 1, 1), 256, 0, stream>>>(
      W3, netT, (size_t)256 * 256, (size_t)4096 * 256, out, bout);
}